// Round 1
// baseline (276.258 us; speedup 1.0000x reference)
//
#include <hip/hip_runtime.h>

typedef unsigned short u16;
typedef __attribute__((ext_vector_type(8))) short bf16x8;
typedef __attribute__((ext_vector_type(4))) float f32x4;
typedef __attribute__((ext_vector_type(4))) short s16x4;

#define OUTW 8448  // 256 + 64*128

// ---- bf16 helpers (RNE; values are finite & bounded here) ----
static __device__ __forceinline__ float bf2f(u16 u) {
    union { unsigned int i; float f; } x; x.i = ((unsigned int)u) << 16; return x.f;
}
static __device__ __forceinline__ u16 f2bf(float f) {
    union { float f; unsigned int i; } x; x.f = f;
    unsigned int lsb = (x.i >> 16) & 1u;
    return (u16)((x.i + 0x7fffu + lsb) >> 16);
}

// ============================================================
// Kernel A: X(32*1024 x 768) @ [Wf | Ws](768 x 192), bf16 MFMA.
//  cols 0..127 -> fT[b][c][n] (bf16, TRANSPOSED for later MFMA B-frags)
//  cols 128..191 -> sM[b][c][n] = (dot + bs)*sharpness/REG   (f32)
// ============================================================
__global__ __launch_bounds__(256, 2) void k_gemm1(
    const float* __restrict__ x, const float* __restrict__ Wf, const float* __restrict__ bf_,
    const float* __restrict__ Ws, const float* __restrict__ bs_, const float* __restrict__ sharp,
    u16* __restrict__ fT, float* __restrict__ sM)
{
    __shared__ u16 Asm[128][72];   // +8 pad: row stride 144B -> 2-way bank (free)
    __shared__ u16 Bsm[64][72];    // stored transposed [n][k]
    const int tid  = threadIdx.x;
    const int lane = tid & 63;
    const int w    = tid >> 6;
    const int bm = blockIdx.x, bn = blockIdx.y;
    const int b  = bm >> 3;
    const int n0 = (bm & 7) << 7;
    const float* Abase = x + ((size_t)b * 1025 + 1 + n0) * 768;  // fi = x[:,1:]
    const float* Bsrc; int bstride, coff;
    if (bn < 2) { Bsrc = Wf; bstride = 128; coff = bn * 64; }
    else        { Bsrc = Ws; bstride = 64;  coff = 0; }

    f32x4 acc[2][4] = {};
    const int arow = tid >> 4;          // 0..15
    const int acol = (tid & 15) << 2;   // 0..60
    const int bc   = tid & 63;
    const int bkg  = tid >> 6;          // 0..3

    for (int ks = 0; ks < 12; ++ks) {
        const int k0 = ks * 64;
        // stage A tile 128x64 (f32 -> bf16)
        #pragma unroll
        for (int pp = 0; pp < 8; ++pp) {
            const int r = arow + pp * 16;
            const float4 v = *(const float4*)(Abase + (size_t)r * 768 + k0 + acol);
            u16* dA = &Asm[r][acol];
            dA[0] = f2bf(v.x); dA[1] = f2bf(v.y); dA[2] = f2bf(v.z); dA[3] = f2bf(v.w);
        }
        // stage B^T tile [64 cols][64 k]
        {
            u16 tmp[16];
            #pragma unroll
            for (int i = 0; i < 16; ++i)
                tmp[i] = f2bf(Bsrc[(size_t)(k0 + bkg * 16 + i) * bstride + coff + bc]);
            u16* dB = &Bsm[bc][bkg * 16];
            *(s16x4*)(dB)      = *(const s16x4*)(tmp);
            *(s16x4*)(dB + 4)  = *(const s16x4*)(tmp + 4);
            *(s16x4*)(dB + 8)  = *(const s16x4*)(tmp + 8);
            *(s16x4*)(dB + 12) = *(const s16x4*)(tmp + 12);
        }
        __syncthreads();
        #pragma unroll
        for (int kk = 0; kk < 2; ++kk) {
            const int kb = kk * 32 + ((lane >> 4) << 3);
            bf16x8 af[2], bfr[4];
            #pragma unroll
            for (int mt = 0; mt < 2; ++mt)
                af[mt] = *(const bf16x8*)&Asm[w * 32 + mt * 16 + (lane & 15)][kb];
            #pragma unroll
            for (int nt = 0; nt < 4; ++nt)
                bfr[nt] = *(const bf16x8*)&Bsm[nt * 16 + (lane & 15)][kb];
            #pragma unroll
            for (int mt = 0; mt < 2; ++mt)
                #pragma unroll
                for (int nt = 0; nt < 4; ++nt)
                    acc[mt][nt] = __builtin_amdgcn_mfma_f32_16x16x32_bf16(af[mt], bfr[nt], acc[mt][nt], 0, 0, 0);
        }
        __syncthreads();
    }
    // epilogue: D row = w*32+mt*16+(lane>>4)*4+r (token), col = nt*16+(lane&15)
    const int rbase = (lane >> 4) << 2;
    const int cl = lane & 15;
    if (bn < 2) {
        #pragma unroll
        for (int mt = 0; mt < 2; ++mt) {
            const int nbase = n0 + w * 32 + mt * 16 + rbase;
            #pragma unroll
            for (int nt = 0; nt < 4; ++nt) {
                const int c = bn * 64 + nt * 16 + cl;
                const float bias = bf_[c];
                u16 pk[4];
                #pragma unroll
                for (int r = 0; r < 4; ++r) pk[r] = f2bf(acc[mt][nt][r] + bias);
                *(s16x4*)&fT[((size_t)b * 128 + c) * 1024 + nbase] = *(const s16x4*)pk;
            }
        }
    } else {
        const float sc = sharp[0] * 10.0f;  // sharpness / REG
        #pragma unroll
        for (int mt = 0; mt < 2; ++mt) {
            const int nbase = n0 + w * 32 + mt * 16 + rbase;
            #pragma unroll
            for (int nt = 0; nt < 4; ++nt) {
                const int cm = nt * 16 + cl;
                const float bias = bs_[cm];
                float4 v;
                v.x = (acc[mt][nt][0] + bias) * sc;
                v.y = (acc[mt][nt][1] + bias) * sc;
                v.z = (acc[mt][nt][2] + bias) * sc;
                v.w = (acc[mt][nt][3] + bias) * sc;
                *(float4*)&sM[((size_t)b * 64 + cm) * 1024 + nbase] = v;
            }
        }
    }
}

// ============================================================
// Kernel C: per-batch Sinkhorn (non-log scaled form).
//  K = exp(M - rowmax) (bf16 LDS), dust row == 1 implicit.
//  5x { alpha = a/(K beta) ; beta = b/(K^T alpha) }, p = alpha*K*beta.
//  Exactly equivalent to the reference's 5 logsumexp iterations
//  (constant dust row => colmax == 0, dust_bin cancels from p[0:64]).
// ============================================================
__global__ __launch_bounds__(1024, 1) void k_sinkhorn(
    const float* __restrict__ sM, u16* __restrict__ p_out)
{
    __shared__ u16   Ksm[64][1024];
    __shared__ float beta[1024];
    __shared__ float alpha[65];
    const int b = blockIdx.x;
    const int tid = threadIdx.x;
    const int lane = tid & 63;
    const int w = tid >> 6;            // 16 waves
    const float* Mb = sM + (size_t)b * 64 * 1024;

    #pragma unroll
    for (int i = 0; i < 4; ++i) {
        const int c = w + 16 * i;
        const float* row = Mb + (size_t)c * 1024;
        float vals[16]; float mx = -3.4e38f;
        #pragma unroll
        for (int j = 0; j < 16; ++j) { vals[j] = row[lane + 64 * j]; mx = fmaxf(mx, vals[j]); }
        #pragma unroll
        for (int off = 32; off > 0; off >>= 1) mx = fmaxf(mx, __shfl_xor(mx, off));
        #pragma unroll
        for (int j = 0; j < 16; ++j) Ksm[c][lane + 64 * j] = f2bf(__expf(vals[j] - mx));
    }
    beta[tid] = 1.0f;
    __syncthreads();

    const float a_c = 1.0f / 1024.0f, a_dust = 960.0f / 1024.0f, b_n = 1.0f / 1024.0f;
    for (int it = 0; it < 5; ++it) {
        // alpha: wave-parallel row reductions (reads previous beta)
        #pragma unroll
        for (int i = 0; i < 4; ++i) {
            const int c = w + 16 * i;
            float s = 0.f;
            #pragma unroll
            for (int j = 0; j < 16; ++j)
                s += bf2f(Ksm[c][lane + 64 * j]) * beta[lane + 64 * j];
            #pragma unroll
            for (int off = 32; off > 0; off >>= 1) s += __shfl_xor(s, off);
            if (lane == 0) alpha[c] = a_c / s;
        }
        if (w == 0) {  // dust row: K == 1 -> sum(beta)
            float s = 0.f;
            #pragma unroll
            for (int j = 0; j < 16; ++j) s += beta[lane + 64 * j];
            #pragma unroll
            for (int off = 32; off > 0; off >>= 1) s += __shfl_xor(s, off);
            if (lane == 0) alpha[64] = a_dust / s;
        }
        __syncthreads();
        // beta: thread-per-column
        float s = alpha[64];
        #pragma unroll 16
        for (int c = 0; c < 64; ++c) s += bf2f(Ksm[c][tid]) * alpha[c];
        beta[tid] = b_n / s;
        __syncthreads();
    }
    const float bnv = beta[tid];
    u16* pc = p_out + (size_t)b * 64 * 1024 + tid;
    #pragma unroll 8
    for (int c = 0; c < 64; ++c)
        pc[(size_t)c * 1024] = f2bf(alpha[c] * bf2f(Ksm[c][tid]) * bnv);
}

// ============================================================
// Kernel D: v_agg = 2*p@f - rowsum(p)*anchors  (per batch, MFMA,
// fragments straight from global: p row-major, fT transposed)
// ============================================================
__global__ __launch_bounds__(1024, 1) void k_agg(
    const u16* __restrict__ p, const u16* __restrict__ fT,
    const float* __restrict__ anchors, float* __restrict__ out)
{
    __shared__ float ps[64];
    const int b = blockIdx.x;
    const int tid = threadIdx.x;
    const int lane = tid & 63;
    const int w = tid >> 6;        // 16 waves
    // p row sums
    {
        const int c = tid >> 4;
        const int j = tid & 15;
        const u16* pr = p + ((size_t)b * 64 + c) * 1024 + j * 64;
        float s = 0.f;
        #pragma unroll 16
        for (int i = 0; i < 64; ++i) s += bf2f(pr[i]);
        #pragma unroll
        for (int off = 8; off > 0; off >>= 1) s += __shfl_xor(s, off);
        if (j == 0) ps[c] = s;
    }
    __syncthreads();
    const int mt = w & 3;    // m-tile (c rows)
    const int ng = w >> 2;   // 32-col group
    const u16* arow  = p  + ((size_t)b * 64  + mt * 16 + (lane & 15)) * 1024 + ((lane >> 4) << 3);
    const u16* brow0 = fT + ((size_t)b * 128 + ng * 32 + (lane & 15)) * 1024 + ((lane >> 4) << 3);
    const u16* brow1 = brow0 + 16 * 1024;
    f32x4 acc[2] = {};
    for (int ks = 0; ks < 32; ++ks) {
        const int k0 = ks * 32;
        bf16x8 a  = *(const bf16x8*)(arow  + k0);
        bf16x8 b0 = *(const bf16x8*)(brow0 + k0);
        bf16x8 b1 = *(const bf16x8*)(brow1 + k0);
        acc[0] = __builtin_amdgcn_mfma_f32_16x16x32_bf16(a, b0, acc[0], 0, 0, 0);
        acc[1] = __builtin_amdgcn_mfma_f32_16x16x32_bf16(a, b1, acc[1], 0, 0, 0);
    }
    #pragma unroll
    for (int nt = 0; nt < 2; ++nt) {
        const int d = ng * 32 + nt * 16 + (lane & 15);
        #pragma unroll
        for (int r = 0; r < 4; ++r) {
            const int c = mt * 16 + ((lane >> 4) << 2) + r;
            out[(size_t)b * OUTW + 256 + c * 128 + d] = 2.0f * acc[nt][r] - ps[c] * anchors[c * 128 + d];
        }
    }
}

// ============================================================
// Kernel B2: v_global partials = x[:,0,:] @ Wt  (pure f32, k-split)
// ============================================================
__global__ void k_vglobal(const float* __restrict__ x, const float* __restrict__ Wt,
                          float* __restrict__ vg)
{
    const int kc = blockIdx.x >> 5;
    const int b  = blockIdx.x & 31;
    const int d  = threadIdx.x;
    const float* xr = x  + (size_t)b * (1025 * 768) + kc * 96;
    const float* wp = Wt + (size_t)kc * 96 * 256 + d;
    float acc = 0.f;
    #pragma unroll 8
    for (int k = 0; k < 96; ++k) acc += xr[k] * wp[(size_t)k * 256];
    vg[(size_t)blockIdx.x * 256 + d] = acc;
}

// ============================================================
// Kernel E: assemble v_global (+bt), L2-normalize whole row in place
// ============================================================
__global__ __launch_bounds__(256) void k_norm(const float* __restrict__ vg, const float* __restrict__ bt,
                                              float* __restrict__ out)
{
    const int b = blockIdx.x;
    const int t = threadIdx.x;
    float vals[33];
    float ss = 0.f;
    {
        float v = bt[t];
        #pragma unroll
        for (int kc = 0; kc < 8; ++kc) v += vg[(size_t)(kc * 32 + b) * 256 + t];
        vals[0] = v; ss += v * v;
    }
    #pragma unroll
    for (int j = 1; j < 33; ++j) {
        const float v = out[(size_t)b * OUTW + j * 256 + t];
        vals[j] = v; ss += v * v;
    }
    #pragma unroll
    for (int off = 32; off > 0; off >>= 1) ss += __shfl_xor(ss, off);
    __shared__ float part[4];
    if ((t & 63) == 0) part[t >> 6] = ss;
    __syncthreads();
    const float tot = part[0] + part[1] + part[2] + part[3];
    const float inv = 1.0f / fmaxf(sqrtf(tot), 1e-12f);
    #pragma unroll
    for (int j = 0; j < 33; ++j)
        out[(size_t)b * OUTW + j * 256 + t] = vals[j] * inv;
}

extern "C" void kernel_launch(void* const* d_in, const int* in_sizes, int n_in,
                              void* d_out, int out_size, void* d_ws, size_t ws_size,
                              hipStream_t stream)
{
    const float* x      = (const float*)d_in[0];
    const float* Wf     = (const float*)d_in[1];
    const float* bf_    = (const float*)d_in[2];
    const float* Ws     = (const float*)d_in[3];
    const float* bs_    = (const float*)d_in[4];
    const float* Wt     = (const float*)d_in[5];
    const float* bt     = (const float*)d_in[6];
    const float* anchors= (const float*)d_in[7];
    // d_in[8] = dust_bin: provably cancels out of p[0:64] (constant row potential)
    const float* sharp  = (const float*)d_in[9];

    char* ws = (char*)d_ws;
    u16*   fT = (u16*)(ws);                 //  8,388,608 B : f^T bf16 (B,128,1024)
    float* sM = (float*)(ws + 8388608);     //  8,388,608 B : M f32   (B,64,1024)
    u16*   p  = (u16*)(ws + 16777216);      //  4,194,304 B : p bf16  (B,64,1024)
    float* vg = (float*)(ws + 20971520);    //    262,144 B : v_global partials (8,32,256)
    float* out = (float*)d_out;

    k_gemm1   <<<dim3(256, 3), 256,  0, stream>>>(x, Wf, bf_, Ws, bs_, sharp, fT, sM);
    k_vglobal <<<dim3(256),    256,  0, stream>>>(x, Wt, vg);
    k_sinkhorn<<<dim3(32),     1024, 0, stream>>>(sM, p);
    k_agg     <<<dim3(32),     1024, 0, stream>>>(p, fT, anchors, out);
    k_norm    <<<dim3(32),     256,  0, stream>>>(vg, bt, out);
}

// Round 2
// 275.252 us; speedup vs baseline: 1.0037x; 1.0037x over previous
//
#include <hip/hip_runtime.h>

typedef unsigned short u16;
typedef __attribute__((ext_vector_type(8))) short bf16x8;
typedef __attribute__((ext_vector_type(8))) short s16x8;
typedef __attribute__((ext_vector_type(4))) float f32x4;
typedef __attribute__((ext_vector_type(4))) short s16x4;

#define OUTW 8448  // 256 + 64*128

static __device__ __forceinline__ float bf2f(u16 u) {
    union { unsigned int i; float f; } x; x.i = ((unsigned int)u) << 16; return x.f;
}
static __device__ __forceinline__ u16 f2bf(float f) {
    union { float f; unsigned int i; } x; x.f = f;
    unsigned int lsb = (x.i >> 16) & 1u;
    return (u16)((x.i + 0x7fffu + lsb) >> 16);
}

// ============================================================
// Kernel A: X(32768 x 768) @ [Wf | Ws](768 x 192), bf16 MFMA.
// Single pass over x (read once). Block: 128 tokens x 192 cols,
// 512 threads = 8 waves (2M x 4N), BK=64, reg-prefetch staging.
//  cols 0..127 -> fT[b][c][n] bf16 (transposed for k_agg B-frags)
//  cols 128..191 -> sM[b][c][n] = (dot+bs)*sharp/REG  (f32)
// ============================================================
__global__ __launch_bounds__(512, 2) void k_gemm1(
    const float* __restrict__ x, const float* __restrict__ Wf, const float* __restrict__ bf_,
    const float* __restrict__ Ws, const float* __restrict__ bs_, const float* __restrict__ sharp,
    u16* __restrict__ fT, float* __restrict__ sM)
{
    __shared__ u16 Asm[128][72];   // 18432 B (stride 144B)
    __shared__ u16 Bsm[192][72];   // 27648 B, [col][k]
    const int tid  = threadIdx.x;
    const int lane = tid & 63;
    const int w    = tid >> 6;          // 0..7
    const int b    = blockIdx.x >> 3;
    const int n0   = (blockIdx.x & 7) << 7;
    const float* Abase = x + ((size_t)b * 1025 + 1 + n0) * 768;

    // A staging map: row = tid>>2 (0..127), c0 = (tid&3)*16, 4 x float4
    const int arow = tid >> 2;
    const int ac0  = (tid & 3) << 4;
    // B staging map: 3 slots, idx = tid + s*512: kg = idx/192 (0..7), col = idx%192
    int   bkg[3]; const float* bptr[3]; int bstr[3]; int bcol[3];
    #pragma unroll
    for (int s = 0; s < 3; ++s) {
        const int idx = tid + s * 512;
        const int kg  = idx / 192;
        const int col = idx - kg * 192;
        bkg[s] = kg; bcol[s] = col;
        if (col < 128) { bptr[s] = Wf + col; bstr[s] = 128; }
        else           { bptr[s] = Ws + (col - 128); bstr[s] = 64; }
    }

    f32x4 acc[4][3] = {};
    const int wm = w >> 2, wn = w & 3;
    const int wr = wm * 64, wc = wn * 48;

    float4 pa[4];
    float  pb[3][8];

    // prologue load k-tile 0
    #pragma unroll
    for (int q = 0; q < 4; ++q)
        pa[q] = *(const float4*)(Abase + (size_t)arow * 768 + ac0 + q * 4);
    #pragma unroll
    for (int s = 0; s < 3; ++s)
        #pragma unroll
        for (int j = 0; j < 8; ++j)
            pb[s][j] = bptr[s][(size_t)(bkg[s] * 8 + j) * bstr[s]];

    for (int ks = 0; ks < 12; ++ks) {
        // ---- write staged regs -> LDS (f32 -> bf16) ----
        {
            u16 ta[16];
            #pragma unroll
            for (int q = 0; q < 4; ++q) {
                ta[q*4+0] = f2bf(pa[q].x); ta[q*4+1] = f2bf(pa[q].y);
                ta[q*4+2] = f2bf(pa[q].z); ta[q*4+3] = f2bf(pa[q].w);
            }
            *(s16x8*)&Asm[arow][ac0]     = *(const s16x8*)(ta);
            *(s16x8*)&Asm[arow][ac0 + 8] = *(const s16x8*)(ta + 8);
            #pragma unroll
            for (int s = 0; s < 3; ++s) {
                u16 tb[8];
                #pragma unroll
                for (int j = 0; j < 8; ++j) tb[j] = f2bf(pb[s][j]);
                *(s16x8*)&Bsm[bcol[s]][bkg[s] * 8] = *(const s16x8*)(tb);
            }
        }
        __syncthreads();
        // ---- issue global loads for next k-tile (latency hidden under MFMA) ----
        if (ks < 11) {
            const int k0 = (ks + 1) * 64;
            #pragma unroll
            for (int q = 0; q < 4; ++q)
                pa[q] = *(const float4*)(Abase + (size_t)arow * 768 + k0 + ac0 + q * 4);
            #pragma unroll
            for (int s = 0; s < 3; ++s)
                #pragma unroll
                for (int j = 0; j < 8; ++j)
                    pb[s][j] = bptr[s][(size_t)(k0 + bkg[s] * 8 + j) * bstr[s]];
        }
        // ---- compute on LDS tile ----
        #pragma unroll
        for (int kk = 0; kk < 2; ++kk) {
            const int kb = kk * 32 + ((lane >> 4) << 3);
            bf16x8 af[4], bfr[3];
            #pragma unroll
            for (int mt = 0; mt < 4; ++mt)
                af[mt] = *(const bf16x8*)&Asm[wr + mt * 16 + (lane & 15)][kb];
            #pragma unroll
            for (int nt = 0; nt < 3; ++nt)
                bfr[nt] = *(const bf16x8*)&Bsm[wc + nt * 16 + (lane & 15)][kb];
            #pragma unroll
            for (int mt = 0; mt < 4; ++mt)
                #pragma unroll
                for (int nt = 0; nt < 3; ++nt)
                    acc[mt][nt] = __builtin_amdgcn_mfma_f32_16x16x32_bf16(af[mt], bfr[nt], acc[mt][nt], 0, 0, 0);
        }
        __syncthreads();
    }
    // epilogue: D row(token) = wr + mt*16 + (lane>>4)*4 + r ; col = wc + nt*16 + (lane&15)
    const int rbase = (lane >> 4) << 2;
    const int cl = lane & 15;
    const float sc = sharp[0] * 10.0f;  // sharpness / REG
    #pragma unroll
    for (int mt = 0; mt < 4; ++mt) {
        const int nbase = n0 + wr + mt * 16 + rbase;
        #pragma unroll
        for (int nt = 0; nt < 3; ++nt) {
            const int col16 = wc + nt * 16;       // multiple of 16; never straddles 128
            const int c = col16 + cl;
            if (col16 < 128) {
                const float bias = bf_[c];
                u16 pk[4];
                #pragma unroll
                for (int r = 0; r < 4; ++r) pk[r] = f2bf(acc[mt][nt][r] + bias);
                *(s16x4*)&fT[((size_t)b * 128 + c) * 1024 + nbase] = *(const s16x4*)pk;
            } else {
                const int cm = c - 128;
                const float bias = bs_[cm];
                float4 v;
                v.x = (acc[mt][nt][0] + bias) * sc;
                v.y = (acc[mt][nt][1] + bias) * sc;
                v.z = (acc[mt][nt][2] + bias) * sc;
                v.w = (acc[mt][nt][3] + bias) * sc;
                *(float4*)&sM[((size_t)b * 64 + cm) * 1024 + nbase] = v;
            }
        }
    }
}

// ============================================================
// Kernel C: per-batch Sinkhorn, non-log scaled form (validated r1).
// All LDS traffic at b128 floor rate:
//  alpha-step: K rows read as contiguous-1KB b128 (cols 8l+512j+m),
//              beta in permuted layout -> lane-contiguous b32 reads.
//  beta-step : 8x8 per-thread blocks, b128 K reads, shfl_xor reduce.
// Exports p (bf16) and f32 row-sums rs = alpha * (K @ beta_final).
// ============================================================
__global__ __launch_bounds__(1024, 1) void k_sinkhorn(
    const float* __restrict__ sM, u16* __restrict__ p_out, float* __restrict__ rs_out)
{
    __shared__ u16   Ksm[64][1024];   // 131072 B
    __shared__ float betas[1024];     // permuted: betas[l + m*64 + j*512] = beta[8l+512j+m]
    __shared__ float alph[68];        // [0..63] rows, [64] dust
    const int b   = blockIdx.x;
    const int tid = threadIdx.x;
    const int l   = tid & 63;
    const int w   = tid >> 6;          // 0..15
    const float* Mb = sM + (size_t)b * 64 * 1024;

    // ---- exp phase: rows c = w*4+i, cols l*16..+16 ----
    #pragma unroll
    for (int i = 0; i < 4; ++i) {
        const int c = w * 4 + i;
        float v[16];
        #pragma unroll
        for (int q = 0; q < 4; ++q)
            *(float4*)(v + q * 4) = *(const float4*)(Mb + (size_t)c * 1024 + l * 16 + q * 4);
        float mx = v[0];
        #pragma unroll
        for (int j = 1; j < 16; ++j) mx = fmaxf(mx, v[j]);
        #pragma unroll
        for (int off = 32; off > 0; off >>= 1) mx = fmaxf(mx, __shfl_xor(mx, off));
        u16 e[16];
        #pragma unroll
        for (int j = 0; j < 16; ++j) e[j] = f2bf(__expf(v[j] - mx));
        *(s16x8*)&Ksm[c][l * 16]     = *(const s16x8*)(e);
        *(s16x8*)&Ksm[c][l * 16 + 8] = *(const s16x8*)(e + 8);
    }
    betas[tid] = 1.0f;
    __syncthreads();

    const float a_c = 1.0f / 1024.0f, a_dust = 960.0f / 1024.0f, b_n = 1.0f / 1024.0f;
    const int r8 = (l & 7) * 8;              // beta-step row base
    const int cg = w * 8 + (l >> 3);         // beta-step col group (0..127)
    const int bwi = (cg & 63) + ((cg >> 6) << 9);  // betas write base: + m*64

    for (int it = 0; it < 5; ++it) {
        // ---- alpha-step ----
        float bb[16];
        #pragma unroll
        for (int j = 0; j < 2; ++j)
            #pragma unroll
            for (int m = 0; m < 8; ++m)
                bb[j * 8 + m] = betas[l + m * 64 + j * 512];
        float sb = 0.f;
        #pragma unroll
        for (int j = 0; j < 16; ++j) sb += bb[j];
        #pragma unroll
        for (int off = 32; off > 0; off >>= 1) sb += __shfl_xor(sb, off);
        #pragma unroll
        for (int i = 0; i < 4; ++i) {
            const int c = w * 4 + i;
            float s = 0.f;
            #pragma unroll
            for (int j = 0; j < 2; ++j) {
                const bf16x8 kr = *(const bf16x8*)&Ksm[c][8 * l + 512 * j];
                #pragma unroll
                for (int m = 0; m < 8; ++m)
                    s += bf2f((u16)kr[m]) * bb[j * 8 + m];
            }
            #pragma unroll
            for (int off = 32; off > 0; off >>= 1) s += __shfl_xor(s, off);
            if (l == 0) alph[c] = a_c / s;
        }
        if (tid == 0) alph[64] = a_dust / sb;
        __syncthreads();
        // ---- beta-step: 8x8 blocks (rows r8..+8, cols cg*8..+8) ----
        f32x4 a0 = *(const f32x4*)&alph[r8];
        f32x4 a1 = *(const f32x4*)&alph[r8 + 4];
        const float ad = alph[64];
        float sc8[8] = {};
        #pragma unroll
        for (int i = 0; i < 8; ++i) {
            const bf16x8 kb = *(const bf16x8*)&Ksm[r8 + i][cg * 8];
            const float av = (i < 4) ? a0[i] : a1[i - 4];
            #pragma unroll
            for (int m = 0; m < 8; ++m)
                sc8[m] += bf2f((u16)kb[m]) * av;
        }
        #pragma unroll
        for (int off = 1; off < 8; off <<= 1)
            #pragma unroll
            for (int m = 0; m < 8; ++m)
                sc8[m] += __shfl_xor(sc8[m], off);
        if ((l & 7) == 0) {
            #pragma unroll
            for (int m = 0; m < 8; ++m)
                betas[bwi + m * 64] = b_n / (sc8[m] + ad);
        }
        __syncthreads();
    }

    // ---- final pass: p = alpha*K*beta (bf16, coalesced) + rowsums rs = alpha*(K beta) ----
    float bb[16];
    #pragma unroll
    for (int j = 0; j < 2; ++j)
        #pragma unroll
        for (int m = 0; m < 8; ++m)
            bb[j * 8 + m] = betas[l + m * 64 + j * 512];
    #pragma unroll
    for (int i = 0; i < 4; ++i) {
        const int c = w * 4 + i;
        const float ac = alph[c];
        float pv[16]; float s = 0.f;
        #pragma unroll
        for (int j = 0; j < 2; ++j) {
            const bf16x8 kr = *(const bf16x8*)&Ksm[c][8 * l + 512 * j];
            #pragma unroll
            for (int m = 0; m < 8; ++m) {
                const float t = bf2f((u16)kr[m]) * bb[j * 8 + m];
                pv[j * 8 + m] = t; s += t;
            }
        }
        #pragma unroll
        for (int off = 32; off > 0; off >>= 1) s += __shfl_xor(s, off);
        if (l == 0) rs_out[b * 64 + c] = ac * s;
        u16 pk[16];
        #pragma unroll
        for (int j = 0; j < 16; ++j) pk[j] = f2bf(ac * pv[j]);
        u16* pg = p_out + ((size_t)b * 64 + c) * 1024 + 8 * l;
        *(s16x8*)(pg)       = *(const s16x8*)(pk);
        *(s16x8*)(pg + 512) = *(const s16x8*)(pk + 8);
    }
}

// ============================================================
// Kernel D: v_agg = 2*p@f - rs*anchors  (per batch, MFMA,
// fragments straight from global: p row-major, fT transposed)
// ============================================================
__global__ __launch_bounds__(1024, 1) void k_agg(
    const u16* __restrict__ p, const u16* __restrict__ fT,
    const float* __restrict__ rs, const float* __restrict__ anchors,
    float* __restrict__ out)
{
    const int b = blockIdx.x;
    const int tid = threadIdx.x;
    const int lane = tid & 63;
    const int w = tid >> 6;        // 16 waves
    const int mt = w & 3;          // m-tile (16 cluster rows)
    const int ng = w >> 2;         // 32-col group
    const u16* arow  = p  + ((size_t)b * 64  + mt * 16 + (lane & 15)) * 1024 + ((lane >> 4) << 3);
    const u16* brow0 = fT + ((size_t)b * 128 + ng * 32 + (lane & 15)) * 1024 + ((lane >> 4) << 3);
    const u16* brow1 = brow0 + 16 * 1024;
    f32x4 acc[2] = {};
    for (int ks = 0; ks < 32; ++ks) {
        const int k0 = ks * 32;
        bf16x8 a  = *(const bf16x8*)(arow  + k0);
        bf16x8 b0 = *(const bf16x8*)(brow0 + k0);
        bf16x8 b1 = *(const bf16x8*)(brow1 + k0);
        acc[0] = __builtin_amdgcn_mfma_f32_16x16x32_bf16(a, b0, acc[0], 0, 0, 0);
        acc[1] = __builtin_amdgcn_mfma_f32_16x16x32_bf16(a, b1, acc[1], 0, 0, 0);
    }
    #pragma unroll
    for (int nt = 0; nt < 2; ++nt) {
        const int d = ng * 32 + nt * 16 + (lane & 15);
        #pragma unroll
        for (int r = 0; r < 4; ++r) {
            const int c = mt * 16 + ((lane >> 4) << 2) + r;
            out[(size_t)b * OUTW + 256 + c * 128 + d] = 2.0f * acc[nt][r] - rs[b * 64 + c] * anchors[c * 128 + d];
        }
    }
}

// ============================================================
// Kernel B2: v_global partials = x[:,0,:] @ Wt  (pure f32, k-split)
// ============================================================
__global__ void k_vglobal(const float* __restrict__ x, const float* __restrict__ Wt,
                          float* __restrict__ vg)
{
    const int kc = blockIdx.x >> 5;
    const int b  = blockIdx.x & 31;
    const int d  = threadIdx.x;
    const float* xr = x  + (size_t)b * (1025 * 768) + kc * 96;
    const float* wp = Wt + (size_t)kc * 96 * 256 + d;
    float acc = 0.f;
    #pragma unroll 8
    for (int k = 0; k < 96; ++k) acc += xr[k] * wp[(size_t)k * 256];
    vg[(size_t)blockIdx.x * 256 + d] = acc;
}

// ============================================================
// Kernel E: assemble v_global (+bt), L2-normalize whole row in place
// ============================================================
__global__ __launch_bounds__(256) void k_norm(const float* __restrict__ vg, const float* __restrict__ bt,
                                              float* __restrict__ out)
{
    const int b = blockIdx.x;
    const int t = threadIdx.x;
    float vals[33];
    float ss = 0.f;
    {
        float v = bt[t];
        #pragma unroll
        for (int kc = 0; kc < 8; ++kc) v += vg[(size_t)(kc * 32 + b) * 256 + t];
        vals[0] = v; ss += v * v;
    }
    #pragma unroll
    for (int j = 1; j < 33; ++j) {
        const float v = out[(size_t)b * OUTW + j * 256 + t];
        vals[j] = v; ss += v * v;
    }
    #pragma unroll
    for (int off = 32; off > 0; off >>= 1) ss += __shfl_xor(ss, off);
    __shared__ float part[4];
    if ((t & 63) == 0) part[t >> 6] = ss;
    __syncthreads();
    const float tot = part[0] + part[1] + part[2] + part[3];
    const float inv = 1.0f / fmaxf(sqrtf(tot), 1e-12f);
    #pragma unroll
    for (int j = 0; j < 33; ++j)
        out[(size_t)b * OUTW + j * 256 + t] = vals[j] * inv;
}

extern "C" void kernel_launch(void* const* d_in, const int* in_sizes, int n_in,
                              void* d_out, int out_size, void* d_ws, size_t ws_size,
                              hipStream_t stream)
{
    const float* x      = (const float*)d_in[0];
    const float* Wf     = (const float*)d_in[1];
    const float* bf_    = (const float*)d_in[2];
    const float* Ws     = (const float*)d_in[3];
    const float* bs_    = (const float*)d_in[4];
    const float* Wt     = (const float*)d_in[5];
    const float* bt     = (const float*)d_in[6];
    const float* anchors= (const float*)d_in[7];
    // d_in[8] = dust_bin: cancels out of p[0:64] (constant row potential)
    const float* sharp  = (const float*)d_in[9];

    char* ws = (char*)d_ws;
    u16*   fT = (u16*)(ws);                 //  8,388,608 B : f^T bf16 (B,128,1024)
    float* sM = (float*)(ws + 8388608);     //  8,388,608 B : M f32   (B,64,1024)
    u16*   p  = (u16*)(ws + 16777216);      //  4,194,304 B : p bf16  (B,64,1024)
    float* vg = (float*)(ws + 20971520);    //    262,144 B : v_global partials (8,32,256)
    float* rs = (float*)(ws + 21233664);    //      8,192 B : rowsums (32,64)
    float* out = (float*)d_out;

    k_gemm1   <<<dim3(256), 512,  0, stream>>>(x, Wf, bf_, Ws, bs_, sharp, fT, sM);
    k_vglobal <<<dim3(256), 256,  0, stream>>>(x, Wt, vg);
    k_sinkhorn<<<dim3(32),  1024, 0, stream>>>(sM, p, rs);
    k_agg     <<<dim3(32),  1024, 0, stream>>>(p, fT, rs, anchors, out);
    k_norm    <<<dim3(32),  256,  0, stream>>>(vg, bt, out);
}

// Round 3
// 256.673 us; speedup vs baseline: 1.0763x; 1.0724x over previous
//
#include <hip/hip_runtime.h>

typedef unsigned short u16;
typedef __attribute__((ext_vector_type(8))) short bf16x8;
typedef __attribute__((ext_vector_type(8))) short s16x8;
typedef __attribute__((ext_vector_type(4))) float f32x4;
typedef __attribute__((ext_vector_type(4))) short s16x4;

#define OUTW 8448  // 256 + 64*128

static __device__ __forceinline__ float bf2f(u16 u) {
    union { unsigned int i; float f; } x; x.i = ((unsigned int)u) << 16; return x.f;
}
static __device__ __forceinline__ u16 f2bf(float f) {
    union { float f; unsigned int i; } x; x.f = f;
    unsigned int lsb = (x.i >> 16) & 1u;
    return (u16)((x.i + 0x7fffu + lsb) >> 16);
}
// LDS column swizzle for Ksm (u16 index, 8-aligned cols): permutes 16B slots
// within each 128B group. Conflict-free for all 4 access patterns used:
//  - row-wide reads (row fixed -> uniform XOR)
//  - beta-step 8x8 blocks (rows (l&7)*8+i -> (r>>3)=l&7 per-lane distinct)
//  - MFMA A-frag reads (rows mt*16+(l&15): (r^(r>>3))&7 hits each slot 2x = free)
static __device__ __forceinline__ int kswz(int r, int c) {
    return c ^ (((r ^ (r >> 3)) & 7) << 3);
}

// ============================================================
// Kernel P: (blocks 0..11)  pack [Wf|Ws] -> Bp bf16 [12][192][64]
//           (blocks 12..267) v_global partials = x[:,0,:] @ Wt (f32, k-split 8)
// ============================================================
__global__ __launch_bounds__(256) void k_pre(
    const float* __restrict__ x, const float* __restrict__ Wf, const float* __restrict__ Ws,
    const float* __restrict__ Wt, u16* __restrict__ Bp, float* __restrict__ vg)
{
    const int bid = blockIdx.x, tid = threadIdx.x;
    if (bid < 12) {
        __shared__ float Wl[64][193];   // k-slab transposed staging (+1 pad col)
        const int t = bid;
        #pragma unroll 4
        for (int i = 0; i < 32; ++i) {
            const int idx = i * 256 + tid, r = idx >> 7, c = idx & 127;
            Wl[r][c] = Wf[(size_t)(t * 64 + r) * 128 + c];
        }
        #pragma unroll 4
        for (int i = 0; i < 16; ++i) {
            const int idx = i * 256 + tid, r = idx >> 6, c = idx & 63;
            Wl[r][128 + c] = Ws[(size_t)(t * 64 + r) * 64 + c];
        }
        __syncthreads();
        #pragma unroll
        for (int i = 0; i < 6; ++i) {
            const int ch = i * 256 + tid, c = ch >> 3, j0 = (ch & 7) << 3;
            u16 pk[8];
            #pragma unroll
            for (int j = 0; j < 8; ++j) pk[j] = f2bf(Wl[j0 + j][c]);
            *(s16x8*)&Bp[((size_t)t * 192 + c) * 64 + j0] = *(const s16x8*)pk;
        }
    } else {
        const int blk = bid - 12;
        const int kc = blk >> 5, b = blk & 31, d = tid;
        const float* xr = x + (size_t)b * (1025 * 768) + kc * 96;
        const float* wp = Wt + (size_t)kc * 96 * 256 + d;
        float acc = 0.f;
        #pragma unroll 8
        for (int k = 0; k < 96; ++k) acc += xr[k] * wp[(size_t)k * 256];
        vg[(size_t)blk * 256 + d] = acc;
    }
}

// ============================================================
// Kernel A: X(32768 x 768) @ Bp(768 x 192), bf16 MFMA.
// M-tile 64 -> 512 blocks = 2/CU. 512 thr = 8 waves (2M x 4N).
// B-frags loaded global->reg from pre-packed Bp (L2-resident).
// A double-buffered in LDS, reg-prefetched. ONE barrier/K-step.
//  cols 0..127 -> fT[b][c][n] bf16 (transposed, for k_tail B-frags)
//  cols 128..191 -> sM[b][c][n] = (dot+bs)*sharp/REG  (f32)
// ============================================================
__global__ __launch_bounds__(512, 4) void k_gemm1(
    const float* __restrict__ x, const u16* __restrict__ Bp,
    const float* __restrict__ bf_, const float* __restrict__ bs_, const float* __restrict__ sharp,
    u16* __restrict__ fT, float* __restrict__ sM)
{
    __shared__ u16 Asm[2][64][72];   // 2 x 9216 B, +8 pad (2-way bank = free)
    const int tid  = threadIdx.x;
    const int lane = tid & 63;
    const int w    = tid >> 6;          // 0..7
    const int wm   = w >> 2, wn = w & 3;
    const int b    = blockIdx.x >> 4;
    const int n0   = (blockIdx.x & 15) << 6;
    const float* Abase = x + ((size_t)b * 1025 + 1 + n0) * 768;  // fi = x[:,1:]

    // A staging: row = tid>>3 (0..63), k0 = (tid&7)*8 -> 8 f32 -> 1 b128 LDS write
    const int arow = tid >> 3, ak0 = (tid & 7) << 3;
    const float* aptr = Abase + (size_t)arow * 768 + ak0;
    // B frag base: col = wn*48 + nt*16 + (lane&15), within-tile k = kk*32 + (lane>>4)*8
    const int fk = (lane >> 4) << 3;
    const u16* bbase = Bp + (size_t)(wn * 48 + (lane & 15)) * 64 + fk;

    f32x4 acc[2][3] = {};
    float4 pa[2];
    bf16x8 bcur[6], bnxt[6];

    // ---- prologue: tile 0 ----
    pa[0] = *(const float4*)(aptr);
    pa[1] = *(const float4*)(aptr + 4);
    #pragma unroll
    for (int nt = 0; nt < 3; ++nt)
        #pragma unroll
        for (int kk = 0; kk < 2; ++kk)
            bcur[nt * 2 + kk] = *(const bf16x8*)(bbase + nt * 1024 + kk * 32);
    {
        u16 t8[8];
        t8[0] = f2bf(pa[0].x); t8[1] = f2bf(pa[0].y); t8[2] = f2bf(pa[0].z); t8[3] = f2bf(pa[0].w);
        t8[4] = f2bf(pa[1].x); t8[5] = f2bf(pa[1].y); t8[6] = f2bf(pa[1].z); t8[7] = f2bf(pa[1].w);
        *(s16x8*)&Asm[0][arow][ak0] = *(const s16x8*)t8;
    }
    pa[0] = *(const float4*)(aptr + 64);
    pa[1] = *(const float4*)(aptr + 68);
    __syncthreads();

    for (int t = 0; t < 12; ++t) {
        const int cur = t & 1;
        if (t < 11) {
            // B-frags for t+1 (global->reg, L2-hit ~200cy, hidden under MFMA)
            const u16* bp1 = bbase + (size_t)(t + 1) * 12288;
            #pragma unroll
            for (int nt = 0; nt < 3; ++nt)
                #pragma unroll
                for (int kk = 0; kk < 2; ++kk)
                    bnxt[nt * 2 + kk] = *(const bf16x8*)(bp1 + nt * 1024 + kk * 32);
            // A(t+1): cvt staged regs -> other LDS buffer (read by compute(t+1))
            u16 t8[8];
            t8[0] = f2bf(pa[0].x); t8[1] = f2bf(pa[0].y); t8[2] = f2bf(pa[0].z); t8[3] = f2bf(pa[0].w);
            t8[4] = f2bf(pa[1].x); t8[5] = f2bf(pa[1].y); t8[6] = f2bf(pa[1].z); t8[7] = f2bf(pa[1].w);
            *(s16x8*)&Asm[cur ^ 1][arow][ak0] = *(const s16x8*)t8;
        }
        if (t < 10) {
            const float* ap = aptr + (size_t)(t + 2) * 64;
            pa[0] = *(const float4*)(ap);
            pa[1] = *(const float4*)(ap + 4);
        }
        // ---- compute tile t ----
        #pragma unroll
        for (int kk = 0; kk < 2; ++kk) {
            bf16x8 af[2];
            af[0] = *(const bf16x8*)&Asm[cur][wm * 32 + (lane & 15)][kk * 32 + fk];
            af[1] = *(const bf16x8*)&Asm[cur][wm * 32 + 16 + (lane & 15)][kk * 32 + fk];
            #pragma unroll
            for (int nt = 0; nt < 3; ++nt) {
                acc[0][nt] = __builtin_amdgcn_mfma_f32_16x16x32_bf16(af[0], bcur[nt * 2 + kk], acc[0][nt], 0, 0, 0);
                acc[1][nt] = __builtin_amdgcn_mfma_f32_16x16x32_bf16(af[1], bcur[nt * 2 + kk], acc[1][nt], 0, 0, 0);
            }
        }
        if (t < 11) {
            #pragma unroll
            for (int i = 0; i < 6; ++i) bcur[i] = bnxt[i];
        }
        __syncthreads();
    }

    // epilogue: token = n0 + wm*32 + mt*16 + (lane>>4)*4 + r ; col = wn*48 + nt*16 + (lane&15)
    const int rbase = (lane >> 4) << 2;
    const int cl = lane & 15;
    const float sc = sharp[0] * 10.0f;  // sharpness / REG
    #pragma unroll
    for (int mt = 0; mt < 2; ++mt) {
        const int nbase = n0 + wm * 32 + mt * 16 + rbase;
        #pragma unroll
        for (int nt = 0; nt < 3; ++nt) {
            const int col16 = wn * 48 + nt * 16;   // 16-aligned; never straddles 128
            const int c = col16 + cl;
            if (col16 < 128) {
                const float bias = bf_[c];
                u16 pk[4];
                #pragma unroll
                for (int r = 0; r < 4; ++r) pk[r] = f2bf(acc[mt][nt][r] + bias);
                *(s16x4*)&fT[((size_t)b * 128 + c) * 1024 + nbase] = *(const s16x4*)pk;
            } else {
                const int cm = c - 128;
                const float bias = bs_[cm];
                float4 v;
                v.x = (acc[mt][nt][0] + bias) * sc;
                v.y = (acc[mt][nt][1] + bias) * sc;
                v.z = (acc[mt][nt][2] + bias) * sc;
                v.w = (acc[mt][nt][3] + bias) * sc;
                *(float4*)&sM[((size_t)b * 64 + cm) * 1024 + nbase] = v;
            }
        }
    }
}

// ============================================================
// Kernel T: per-batch fused tail. 32 blocks x 1024 thr (16 waves).
//  1) K = exp(M - rowmax) -> Ksm bf16 LDS (swizzled cols)
//  2) 5x Sinkhorn {alpha = a/(K beta); beta = b/(K^T alpha)}  (validated r1/r2:
//     dust row == 1 implicit; dust_bin cancels from p[0:64])
//  3) p = alpha*K*beta written back IN PLACE into Ksm + f32 rowsums
//  4) v_agg = 2*p@f - rs*anchors via MFMA (p from LDS, fT from global)
//  5) v_global assemble (+bt) and full-row L2 normalize, write out
// ============================================================
__global__ __launch_bounds__(1024, 1) void k_tail(
    const float* __restrict__ sM, const u16* __restrict__ fT,
    const float* __restrict__ vg, const float* __restrict__ bt,
    const float* __restrict__ anchors, float* __restrict__ out)
{
    __shared__ u16   Ksm[64][1024];   // 131072 B (swizzled via kswz)
    __shared__ float betas[1024];     // permuted: betas[l + m*64 + j*512] = beta[8l+512j+m]
    __shared__ float alph[68];
    __shared__ float rsL[64];
    __shared__ float sred[16];
    const int b = blockIdx.x, tid = threadIdx.x, l = tid & 63, w = tid >> 6;
    const float* Mb = sM + (size_t)b * 64 * 1024;

    // ---- phase 1: exp ----
    #pragma unroll
    for (int i = 0; i < 4; ++i) {
        const int c = w * 4 + i;
        float v[16];
        #pragma unroll
        for (int q = 0; q < 4; ++q)
            *(float4*)(v + q * 4) = *(const float4*)(Mb + (size_t)c * 1024 + l * 16 + q * 4);
        float mx = v[0];
        #pragma unroll
        for (int j = 1; j < 16; ++j) mx = fmaxf(mx, v[j]);
        #pragma unroll
        for (int off = 32; off > 0; off >>= 1) mx = fmaxf(mx, __shfl_xor(mx, off));
        u16 e[16];
        #pragma unroll
        for (int j = 0; j < 16; ++j) e[j] = f2bf(__expf(v[j] - mx));
        *(s16x8*)&Ksm[c][kswz(c, l * 16)]     = *(const s16x8*)(e);
        *(s16x8*)&Ksm[c][kswz(c, l * 16 + 8)] = *(const s16x8*)(e + 8);
    }
    betas[tid] = 1.0f;
    __syncthreads();

    const float a_c = 1.0f / 1024.0f, a_dust = 960.0f / 1024.0f, b_n = 1.0f / 1024.0f;
    const int r8  = (l & 7) * 8;
    const int cg  = w * 8 + (l >> 3);
    const int bwi = (cg & 63) + ((cg >> 6) << 9);

    for (int it = 0; it < 5; ++it) {
        // ---- alpha-step ----
        float bb[16];
        #pragma unroll
        for (int j = 0; j < 2; ++j)
            #pragma unroll
            for (int m = 0; m < 8; ++m)
                bb[j * 8 + m] = betas[l + m * 64 + j * 512];
        float sb = 0.f;
        #pragma unroll
        for (int j = 0; j < 16; ++j) sb += bb[j];
        #pragma unroll
        for (int off = 32; off > 0; off >>= 1) sb += __shfl_xor(sb, off);
        #pragma unroll
        for (int i = 0; i < 4; ++i) {
            const int c = w * 4 + i;
            float s = 0.f;
            #pragma unroll
            for (int j = 0; j < 2; ++j) {
                const bf16x8 kr = *(const bf16x8*)&Ksm[c][kswz(c, 8 * l + 512 * j)];
                #pragma unroll
                for (int m = 0; m < 8; ++m) s += bf2f((u16)kr[m]) * bb[j * 8 + m];
            }
            #pragma unroll
            for (int off = 32; off > 0; off >>= 1) s += __shfl_xor(s, off);
            if (l == 0) alph[c] = a_c / s;
        }
        if (tid == 0) alph[64] = a_dust / sb;
        __syncthreads();
        // ---- beta-step: 8x8 blocks ----
        f32x4 a0 = *(const f32x4*)&alph[r8];
        f32x4 a1 = *(const f32x4*)&alph[r8 + 4];
        const float ad = alph[64];
        float sc8[8] = {};
        #pragma unroll
        for (int i = 0; i < 8; ++i) {
            const bf16x8 kb = *(const bf16x8*)&Ksm[r8 + i][kswz(r8 + i, cg * 8)];
            const float av = (i < 4) ? a0[i] : a1[i - 4];
            #pragma unroll
            for (int m = 0; m < 8; ++m) sc8[m] += bf2f((u16)kb[m]) * av;
        }
        #pragma unroll
        for (int off = 1; off < 8; off <<= 1)
            #pragma unroll
            for (int m = 0; m < 8; ++m) sc8[m] += __shfl_xor(sc8[m], off);
        if ((l & 7) == 0) {
            #pragma unroll
            for (int m = 0; m < 8; ++m) betas[bwi + m * 64] = b_n / (sc8[m] + ad);
        }
        __syncthreads();
    }

    // ---- phase 3: p in place + rowsums ----
    {
        float bb[16];
        #pragma unroll
        for (int j = 0; j < 2; ++j)
            #pragma unroll
            for (int m = 0; m < 8; ++m)
                bb[j * 8 + m] = betas[l + m * 64 + j * 512];
        #pragma unroll
        for (int i = 0; i < 4; ++i) {
            const int c = w * 4 + i;
            const float ac = alph[c];
            float s = 0.f;
            u16 pk[16];
            #pragma unroll
            for (int j = 0; j < 2; ++j) {
                const bf16x8 kr = *(const bf16x8*)&Ksm[c][kswz(c, 8 * l + 512 * j)];
                #pragma unroll
                for (int m = 0; m < 8; ++m) {
                    const float tv = bf2f((u16)kr[m]) * bb[j * 8 + m];
                    s += tv;
                    pk[j * 8 + m] = f2bf(ac * tv);
                }
            }
            #pragma unroll
            for (int off = 32; off > 0; off >>= 1) s += __shfl_xor(s, off);
            if (l == 0) rsL[c] = ac * s;
            *(s16x8*)&Ksm[c][kswz(c, 8 * l)]       = *(const s16x8*)(pk);
            *(s16x8*)&Ksm[c][kswz(c, 8 * l + 512)] = *(const s16x8*)(pk + 8);
        }
    }
    __syncthreads();

    // ---- phase 4: agg MFMA (A = p rows from LDS, B = fT rows from global) ----
    const int mt = w & 3, ng = w >> 2;
    const int fk = (l >> 4) << 3;
    const int arow_ = mt * 16 + (l & 15);
    const u16* brow0 = fT + ((size_t)b * 128 + ng * 32 + (l & 15)) * 1024 + fk;
    const u16* brow1 = brow0 + 16 * 1024;
    f32x4 acc2[2] = {};
    #pragma unroll 4
    for (int ks = 0; ks < 32; ++ks) {
        const bf16x8 a  = *(const bf16x8*)&Ksm[arow_][kswz(arow_, ks * 32 + fk)];
        const bf16x8 b0 = *(const bf16x8*)(brow0 + ks * 32);
        const bf16x8 b1 = *(const bf16x8*)(brow1 + ks * 32);
        acc2[0] = __builtin_amdgcn_mfma_f32_16x16x32_bf16(a, b0, acc2[0], 0, 0, 0);
        acc2[1] = __builtin_amdgcn_mfma_f32_16x16x32_bf16(a, b1, acc2[1], 0, 0, 0);
    }

    // ---- phase 5: v_global + full-row L2 norm ----
    float vgv = 0.f, ss = 0.f;
    if (tid < 256) {
        float v = bt[tid];
        #pragma unroll
        for (int kc = 0; kc < 8; ++kc) v += vg[(size_t)(kc * 32 + b) * 256 + tid];
        vgv = v; ss = v * v;
    }
    float vloc[2][4];
    #pragma unroll
    for (int nt = 0; nt < 2; ++nt) {
        const int d = ng * 32 + nt * 16 + (l & 15);
        #pragma unroll
        for (int r = 0; r < 4; ++r) {
            const int c = mt * 16 + ((l >> 4) << 2) + r;
            const float vv = 2.0f * acc2[nt][r] - rsL[c] * anchors[c * 128 + d];
            vloc[nt][r] = vv; ss += vv * vv;
        }
    }
    #pragma unroll
    for (int off = 32; off > 0; off >>= 1) ss += __shfl_xor(ss, off);
    if (l == 0) sred[w] = ss;
    __syncthreads();
    float tot = 0.f;
    #pragma unroll
    for (int i = 0; i < 16; ++i) tot += sred[i];
    const float inv = 1.0f / fmaxf(sqrtf(tot), 1e-12f);
    if (tid < 256) out[(size_t)b * OUTW + tid] = vgv * inv;
    #pragma unroll
    for (int nt = 0; nt < 2; ++nt) {
        const int d = ng * 32 + nt * 16 + (l & 15);
        #pragma unroll
        for (int r = 0; r < 4; ++r) {
            const int c = mt * 16 + ((l >> 4) << 2) + r;
            out[(size_t)b * OUTW + 256 + (size_t)c * 128 + d] = vloc[nt][r] * inv;
        }
    }
}

extern "C" void kernel_launch(void* const* d_in, const int* in_sizes, int n_in,
                              void* d_out, int out_size, void* d_ws, size_t ws_size,
                              hipStream_t stream)
{
    const float* x      = (const float*)d_in[0];
    const float* Wf     = (const float*)d_in[1];
    const float* bf_    = (const float*)d_in[2];
    const float* Ws     = (const float*)d_in[3];
    const float* bs_    = (const float*)d_in[4];
    const float* Wt     = (const float*)d_in[5];
    const float* bt     = (const float*)d_in[6];
    const float* anchors= (const float*)d_in[7];
    // d_in[8] = dust_bin: cancels out of p[0:64] (constant row potential)
    const float* sharp  = (const float*)d_in[9];

    char* ws = (char*)d_ws;
    u16*   fT = (u16*)(ws);                 //  8,388,608 B : f^T bf16 (B,128,1024)
    float* sM = (float*)(ws + 8388608);     //  8,388,608 B : M f32   (B,64,1024)
    u16*   Bp = (u16*)(ws + 16777216);      //    294,912 B : packed B bf16 [12][192][64]
    float* vg = (float*)(ws + 17072128);    //    262,144 B : v_global partials (8,32,256)
    float* out = (float*)d_out;

    k_pre  <<<dim3(268), 256,  0, stream>>>(x, Wf, Ws, Wt, Bp, vg);
    k_gemm1<<<dim3(512), 512,  0, stream>>>(x, Bp, bf_, bs_, sharp, fT, sM);
    k_tail <<<dim3(32),  1024, 0, stream>>>(sM, fT, vg, bt, anchors, out);
}

// Round 4
// 246.030 us; speedup vs baseline: 1.1229x; 1.0433x over previous
//
#include <hip/hip_runtime.h>

typedef unsigned short u16;
typedef __attribute__((ext_vector_type(8))) short bf16x8;
typedef __attribute__((ext_vector_type(8))) short s16x8;
typedef __attribute__((ext_vector_type(4))) float f32x4;
typedef __attribute__((ext_vector_type(4))) short s16x4;

#define OUTW 8448  // 256 + 64*128

static __device__ __forceinline__ float bf2f(u16 u) {
    union { unsigned int i; float f; } x; x.i = ((unsigned int)u) << 16; return x.f;
}
static __device__ __forceinline__ u16 f2bf(float f) {
    union { float f; unsigned int i; } x; x.f = f;
    unsigned int lsb = (x.i >> 16) & 1u;
    return (u16)((x.i + 0x7fffu + lsb) >> 16);
}
// LDS column swizzle for Ksm (u16 index, 8-aligned cols): permutes 16B slots
// within each 128B group. Conflict-free for all access phases used (see r3).
static __device__ __forceinline__ int kswz(int r, int c) {
    return c ^ (((r ^ (r >> 3)) & 7) << 3);
}

// ============================================================
// Kernel P: (blocks 0..11)  pack [Wf|Ws] -> Bp bf16 [12][192][64]
//           (blocks 12..267) v_global partials = x[:,0,:] @ Wt (f32, k-split 8)
// ============================================================
__global__ __launch_bounds__(256) void k_pre(
    const float* __restrict__ x, const float* __restrict__ Wf, const float* __restrict__ Ws,
    const float* __restrict__ Wt, u16* __restrict__ Bp, float* __restrict__ vg)
{
    const int bid = blockIdx.x, tid = threadIdx.x;
    if (bid < 12) {
        __shared__ float Wl[64][193];   // k-slab transposed staging (+1 pad col)
        const int t = bid;
        #pragma unroll 4
        for (int i = 0; i < 32; ++i) {
            const int idx = i * 256 + tid, r = idx >> 7, c = idx & 127;
            Wl[r][c] = Wf[(size_t)(t * 64 + r) * 128 + c];
        }
        #pragma unroll 4
        for (int i = 0; i < 16; ++i) {
            const int idx = i * 256 + tid, r = idx >> 6, c = idx & 63;
            Wl[r][128 + c] = Ws[(size_t)(t * 64 + r) * 64 + c];
        }
        __syncthreads();
        #pragma unroll
        for (int i = 0; i < 6; ++i) {
            const int ch = i * 256 + tid, c = ch >> 3, j0 = (ch & 7) << 3;
            u16 pk[8];
            #pragma unroll
            for (int j = 0; j < 8; ++j) pk[j] = f2bf(Wl[j0 + j][c]);
            *(s16x8*)&Bp[((size_t)t * 192 + c) * 64 + j0] = *(const s16x8*)pk;
        }
    } else {
        const int blk = bid - 12;
        const int kc = blk >> 5, b = blk & 31, d = tid;
        const float* xr = x + (size_t)b * (1025 * 768) + kc * 96;
        const float* wp = Wt + (size_t)kc * 96 * 256 + d;
        float acc = 0.f;
        #pragma unroll 8
        for (int k = 0; k < 96; ++k) acc += xr[k] * wp[(size_t)k * 256];
        vg[(size_t)blk * 256 + d] = acc;
    }
}

// ============================================================
// Kernel A: X(32768 x 768) @ Bp(768 x 192), bf16 MFMA.
// BM=32 -> grid 1024 = 4 blocks/CU (4 independent barrier domains:
// while one block sits in the vmcnt(0) barrier drain, the other three
// compute -- TLP hides the drain that serialized r1-r3).
// 256 thr = 4 waves, each wave: M32 x N48 (2x3 frags), BK=64.
// B-frags global->reg from packed Bp (L2-resident); A dbuf in LDS.
//  cols 0..127 -> fT[b][c][n] bf16 ; cols 128..191 -> sM (f32, *sharp/REG)
// ============================================================
__global__ __launch_bounds__(256, 4) void k_gemm1(
    const float* __restrict__ x, const u16* __restrict__ Bp,
    const float* __restrict__ bf_, const float* __restrict__ bs_, const float* __restrict__ sharp,
    u16* __restrict__ fT, float* __restrict__ sM)
{
    __shared__ u16 Asm[2][32][72];   // 2 x 4608 B
    const int tid  = threadIdx.x;
    const int lane = tid & 63;
    const int w    = tid >> 6;          // 0..3 = N-slice
    const int b    = blockIdx.x >> 5;
    const int n0   = (blockIdx.x & 31) << 5;
    const float* Abase = x + ((size_t)b * 1025 + 1 + n0) * 768;  // fi = x[:,1:]

    // A staging: row = tid>>3 (0..31), k0 = (tid&7)*8 -> 2 float4 -> 1 b128 LDS write
    const int arow = tid >> 3, ak0 = (tid & 7) << 3;
    const float* aptr = Abase + (size_t)arow * 768 + ak0;
    // B frag base: col = w*48 + nt*16 + (lane&15), within-tile k = kk*32 + (lane>>4)*8
    const int fk = (lane >> 4) << 3;
    const u16* bbase = Bp + (size_t)(w * 48 + (lane & 15)) * 64 + fk;

    f32x4 acc[2][3] = {};
    float4 pa[2];
    bf16x8 bcur[6], bnxt[6];

    // ---- prologue: tile 0 ----
    pa[0] = *(const float4*)(aptr);
    pa[1] = *(const float4*)(aptr + 4);
    #pragma unroll
    for (int nt = 0; nt < 3; ++nt)
        #pragma unroll
        for (int kk = 0; kk < 2; ++kk)
            bcur[nt * 2 + kk] = *(const bf16x8*)(bbase + nt * 1024 + kk * 32);
    {
        u16 t8[8];
        t8[0] = f2bf(pa[0].x); t8[1] = f2bf(pa[0].y); t8[2] = f2bf(pa[0].z); t8[3] = f2bf(pa[0].w);
        t8[4] = f2bf(pa[1].x); t8[5] = f2bf(pa[1].y); t8[6] = f2bf(pa[1].z); t8[7] = f2bf(pa[1].w);
        *(s16x8*)&Asm[0][arow][ak0] = *(const s16x8*)t8;
    }
    pa[0] = *(const float4*)(aptr + 64);
    pa[1] = *(const float4*)(aptr + 68);
    __syncthreads();

    for (int t = 0; t < 12; ++t) {
        const int cur = t & 1;
        if (t < 11) {
            // B-frags for t+1 (L2-resident)
            const u16* bp1 = bbase + (size_t)(t + 1) * 12288;
            #pragma unroll
            for (int nt = 0; nt < 3; ++nt)
                #pragma unroll
                for (int kk = 0; kk < 2; ++kk)
                    bnxt[nt * 2 + kk] = *(const bf16x8*)(bp1 + nt * 1024 + kk * 32);
            // A(t+1): cvt staged regs -> other LDS buffer
            u16 t8[8];
            t8[0] = f2bf(pa[0].x); t8[1] = f2bf(pa[0].y); t8[2] = f2bf(pa[0].z); t8[3] = f2bf(pa[0].w);
            t8[4] = f2bf(pa[1].x); t8[5] = f2bf(pa[1].y); t8[6] = f2bf(pa[1].z); t8[7] = f2bf(pa[1].w);
            *(s16x8*)&Asm[cur ^ 1][arow][ak0] = *(const s16x8*)t8;
        }
        if (t < 10) {
            const float* ap = aptr + (size_t)(t + 2) * 64;
            pa[0] = *(const float4*)(ap);
            pa[1] = *(const float4*)(ap + 4);
        }
        // ---- compute tile t ----
        #pragma unroll
        for (int kk = 0; kk < 2; ++kk) {
            bf16x8 af[2];
            af[0] = *(const bf16x8*)&Asm[cur][(lane & 15)][kk * 32 + fk];
            af[1] = *(const bf16x8*)&Asm[cur][16 + (lane & 15)][kk * 32 + fk];
            #pragma unroll
            for (int nt = 0; nt < 3; ++nt) {
                acc[0][nt] = __builtin_amdgcn_mfma_f32_16x16x32_bf16(af[0], bcur[nt * 2 + kk], acc[0][nt], 0, 0, 0);
                acc[1][nt] = __builtin_amdgcn_mfma_f32_16x16x32_bf16(af[1], bcur[nt * 2 + kk], acc[1][nt], 0, 0, 0);
            }
        }
        if (t < 11) {
            #pragma unroll
            for (int i = 0; i < 6; ++i) bcur[i] = bnxt[i];
        }
        __syncthreads();
    }

    // epilogue: token = n0 + mt*16 + (lane>>4)*4 + r ; col = w*48 + nt*16 + (lane&15)
    const int rbase = (lane >> 4) << 2;
    const int cl = lane & 15;
    const float sc = sharp[0] * 10.0f;  // sharpness / REG
    #pragma unroll
    for (int mt = 0; mt < 2; ++mt) {
        const int nbase = n0 + mt * 16 + rbase;
        #pragma unroll
        for (int nt = 0; nt < 3; ++nt) {
            const int col16 = w * 48 + nt * 16;   // 16-aligned; never straddles 128
            const int c = col16 + cl;
            if (col16 < 128) {
                const float bias = bf_[c];
                u16 pk[4];
                #pragma unroll
                for (int r = 0; r < 4; ++r) pk[r] = f2bf(acc[mt][nt][r] + bias);
                *(s16x4*)&fT[((size_t)b * 128 + c) * 1024 + nbase] = *(const s16x4*)pk;
            } else {
                const int cm = c - 128;
                const float bias = bs_[cm];
                float4 v;
                v.x = (acc[mt][nt][0] + bias) * sc;
                v.y = (acc[mt][nt][1] + bias) * sc;
                v.z = (acc[mt][nt][2] + bias) * sc;
                v.w = (acc[mt][nt][3] + bias) * sc;
                *(float4*)&sM[((size_t)b * 64 + cm) * 1024 + nbase] = v;
            }
        }
    }
}

// ============================================================
// Kernel T: per-batch fused tail. 32 blocks x 1024 thr (16 waves).
//  1) K = exp(M - rowmax) -> Ksm bf16 LDS (swizzled cols)
//  2) 5x Sinkhorn {alpha = a/(K beta); beta = b/(K^T alpha)}
//  3) p = alpha*K*beta in place + f32 rowsums
//  4) v_agg = 2*p@f - rs*anchors via MFMA (waves = 2mt x 8ng: halves
//     redundant fT re-reads vs 4x4)
//  5) v_global assemble (+bt) and full-row L2 normalize
// ============================================================
__global__ __launch_bounds__(1024, 1) void k_tail(
    const float* __restrict__ sM, const u16* __restrict__ fT,
    const float* __restrict__ vg, const float* __restrict__ bt,
    const float* __restrict__ anchors, float* __restrict__ out)
{
    __shared__ u16   Ksm[64][1024];   // 131072 B (swizzled via kswz)
    __shared__ float betas[1024];     // permuted: betas[l + m*64 + j*512] = beta[8l+512j+m]
    __shared__ float alph[68];
    __shared__ float rsL[64];
    __shared__ float sred[16];
    const int b = blockIdx.x, tid = threadIdx.x, l = tid & 63, w = tid >> 6;
    const float* Mb = sM + (size_t)b * 64 * 1024;

    // ---- phase 1: exp ----
    #pragma unroll
    for (int i = 0; i < 4; ++i) {
        const int c = w * 4 + i;
        float v[16];
        #pragma unroll
        for (int q = 0; q < 4; ++q)
            *(float4*)(v + q * 4) = *(const float4*)(Mb + (size_t)c * 1024 + l * 16 + q * 4);
        float mx = v[0];
        #pragma unroll
        for (int j = 1; j < 16; ++j) mx = fmaxf(mx, v[j]);
        #pragma unroll
        for (int off = 32; off > 0; off >>= 1) mx = fmaxf(mx, __shfl_xor(mx, off));
        u16 e[16];
        #pragma unroll
        for (int j = 0; j < 16; ++j) e[j] = f2bf(__expf(v[j] - mx));
        *(s16x8*)&Ksm[c][kswz(c, l * 16)]     = *(const s16x8*)(e);
        *(s16x8*)&Ksm[c][kswz(c, l * 16 + 8)] = *(const s16x8*)(e + 8);
    }
    betas[tid] = 1.0f;
    __syncthreads();

    const float a_c = 1.0f / 1024.0f, a_dust = 960.0f / 1024.0f, b_n = 1.0f / 1024.0f;
    const int r8  = (l & 7) * 8;
    const int cg  = w * 8 + (l >> 3);
    const int bwi = (cg & 63) + ((cg >> 6) << 9);

    for (int it = 0; it < 5; ++it) {
        // ---- alpha-step ----
        float bb[16];
        #pragma unroll
        for (int j = 0; j < 2; ++j)
            #pragma unroll
            for (int m = 0; m < 8; ++m)
                bb[j * 8 + m] = betas[l + m * 64 + j * 512];
        float sb = 0.f;
        #pragma unroll
        for (int j = 0; j < 16; ++j) sb += bb[j];
        #pragma unroll
        for (int off = 32; off > 0; off >>= 1) sb += __shfl_xor(sb, off);
        #pragma unroll
        for (int i = 0; i < 4; ++i) {
            const int c = w * 4 + i;
            float s = 0.f;
            #pragma unroll
            for (int j = 0; j < 2; ++j) {
                const bf16x8 kr = *(const bf16x8*)&Ksm[c][kswz(c, 8 * l + 512 * j)];
                #pragma unroll
                for (int m = 0; m < 8; ++m) s += bf2f((u16)kr[m]) * bb[j * 8 + m];
            }
            #pragma unroll
            for (int off = 32; off > 0; off >>= 1) s += __shfl_xor(s, off);
            if (l == 0) alph[c] = a_c / s;
        }
        if (tid == 0) alph[64] = a_dust / sb;
        __syncthreads();
        // ---- beta-step: 8x8 blocks ----
        f32x4 a0 = *(const f32x4*)&alph[r8];
        f32x4 a1 = *(const f32x4*)&alph[r8 + 4];
        const float ad = alph[64];
        float sc8[8] = {};
        #pragma unroll
        for (int i = 0; i < 8; ++i) {
            const bf16x8 kb = *(const bf16x8*)&Ksm[r8 + i][kswz(r8 + i, cg * 8)];
            const float av = (i < 4) ? a0[i] : a1[i - 4];
            #pragma unroll
            for (int m = 0; m < 8; ++m) sc8[m] += bf2f((u16)kb[m]) * av;
        }
        #pragma unroll
        for (int off = 1; off < 8; off <<= 1)
            #pragma unroll
            for (int m = 0; m < 8; ++m) sc8[m] += __shfl_xor(sc8[m], off);
        if ((l & 7) == 0) {
            #pragma unroll
            for (int m = 0; m < 8; ++m) betas[bwi + m * 64] = b_n / (sc8[m] + ad);
        }
        __syncthreads();
    }

    // ---- phase 3: p in place + rowsums ----
    {
        float bb[16];
        #pragma unroll
        for (int j = 0; j < 2; ++j)
            #pragma unroll
            for (int m = 0; m < 8; ++m)
                bb[j * 8 + m] = betas[l + m * 64 + j * 512];
        #pragma unroll
        for (int i = 0; i < 4; ++i) {
            const int c = w * 4 + i;
            const float ac = alph[c];
            float s = 0.f;
            u16 pk[16];
            #pragma unroll
            for (int j = 0; j < 2; ++j) {
                const bf16x8 kr = *(const bf16x8*)&Ksm[c][kswz(c, 8 * l + 512 * j)];
                #pragma unroll
                for (int m = 0; m < 8; ++m) {
                    const float tv = bf2f((u16)kr[m]) * bb[j * 8 + m];
                    s += tv;
                    pk[j * 8 + m] = f2bf(ac * tv);
                }
            }
            #pragma unroll
            for (int off = 32; off > 0; off >>= 1) s += __shfl_xor(s, off);
            if (l == 0) rsL[c] = ac * s;
            *(s16x8*)&Ksm[c][kswz(c, 8 * l)]       = *(const s16x8*)(pk);
            *(s16x8*)&Ksm[c][kswz(c, 8 * l + 512)] = *(const s16x8*)(pk + 8);
        }
    }
    __syncthreads();

    // ---- phase 4: agg MFMA. waves = wmt (2, c-halves) x wng (8, 16-col groups) ----
    const int wng = w & 7, wmt = w >> 3;
    const int fk = (l >> 4) << 3;
    const int ar0 = wmt * 32 + (l & 15);
    const int ar1 = ar0 + 16;
    const u16* brow = fT + ((size_t)b * 128 + wng * 16 + (l & 15)) * 1024 + fk;
    f32x4 acc2[2] = {};
    #pragma unroll 4
    for (int ks = 0; ks < 32; ++ks) {
        const bf16x8 a0 = *(const bf16x8*)&Ksm[ar0][kswz(ar0, ks * 32 + fk)];
        const bf16x8 a1 = *(const bf16x8*)&Ksm[ar1][kswz(ar1, ks * 32 + fk)];
        const bf16x8 b0 = *(const bf16x8*)(brow + ks * 32);
        acc2[0] = __builtin_amdgcn_mfma_f32_16x16x32_bf16(a0, b0, acc2[0], 0, 0, 0);
        acc2[1] = __builtin_amdgcn_mfma_f32_16x16x32_bf16(a1, b0, acc2[1], 0, 0, 0);
    }

    // ---- phase 5: v_global + full-row L2 norm ----
    float vgv = 0.f, ss = 0.f;
    if (tid < 256) {
        float v = bt[tid];
        #pragma unroll
        for (int kc = 0; kc < 8; ++kc) v += vg[(size_t)(kc * 32 + b) * 256 + tid];
        vgv = v; ss = v * v;
    }
    const int d5 = wng * 16 + (l & 15);
    float vloc[2][4];
    #pragma unroll
    for (int mt = 0; mt < 2; ++mt) {
        #pragma unroll
        for (int r = 0; r < 4; ++r) {
            const int c = wmt * 32 + mt * 16 + ((l >> 4) << 2) + r;
            const float vv = 2.0f * acc2[mt][r] - rsL[c] * anchors[c * 128 + d5];
            vloc[mt][r] = vv; ss += vv * vv;
        }
    }
    #pragma unroll
    for (int off = 32; off > 0; off >>= 1) ss += __shfl_xor(ss, off);
    if (l == 0) sred[w] = ss;
    __syncthreads();
    float tot = 0.f;
    #pragma unroll
    for (int i = 0; i < 16; ++i) tot += sred[i];
    const float inv = 1.0f / fmaxf(sqrtf(tot), 1e-12f);
    if (tid < 256) out[(size_t)b * OUTW + tid] = vgv * inv;
    #pragma unroll
    for (int mt = 0; mt < 2; ++mt) {
        #pragma unroll
        for (int r = 0; r < 4; ++r) {
            const int c = wmt * 32 + mt * 16 + ((l >> 4) << 2) + r;
            out[(size_t)b * OUTW + 256 + (size_t)c * 128 + d5] = vloc[mt][r] * inv;
        }
    }
}

extern "C" void kernel_launch(void* const* d_in, const int* in_sizes, int n_in,
                              void* d_out, int out_size, void* d_ws, size_t ws_size,
                              hipStream_t stream)
{
    const float* x      = (const float*)d_in[0];
    const float* Wf     = (const float*)d_in[1];
    const float* bf_    = (const float*)d_in[2];
    const float* Ws     = (const float*)d_in[3];
    const float* bs_    = (const float*)d_in[4];
    const float* Wt     = (const float*)d_in[5];
    const float* bt     = (const float*)d_in[6];
    const float* anchors= (const float*)d_in[7];
    // d_in[8] = dust_bin: cancels out of p[0:64] (constant row potential)
    const float* sharp  = (const float*)d_in[9];

    char* ws = (char*)d_ws;
    u16*   fT = (u16*)(ws);                 //  8,388,608 B : f^T bf16 (B,128,1024)
    float* sM = (float*)(ws + 8388608);     //  8,388,608 B : M f32   (B,64,1024)
    u16*   Bp = (u16*)(ws + 16777216);      //    294,912 B : packed B bf16 [12][192][64]
    float* vg = (float*)(ws + 17072128);    //    262,144 B : v_global partials (8,32,256)
    float* out = (float*)d_out;

    k_pre  <<<dim3(268),  256,  0, stream>>>(x, Wf, Ws, Wt, Bp, vg);
    k_gemm1<<<dim3(1024), 256,  0, stream>>>(x, Bp, bf_, bs_, sharp, fT, sM);
    k_tail <<<dim3(32),   1024, 0, stream>>>(sM, fT, vg, bt, anchors, out);
}